// Round 1
// baseline (521.623 us; speedup 1.0000x reference)
//
#include <hip/hip_runtime.h>
#include <hip/hip_fp16.h>
#include <hip/hip_cooperative_groups.h>
#include <math.h>

namespace cg = cooperative_groups;

// GraphSAGE mean, 2 layers. F_IN=5, F_HID=5, F_OUT=10.
// R17 = R16 fused into ONE cooperative kernel (grid.sync between phases).
// Theory: ~60-70us of the 200us wall is inter-dispatch gap (4 serialized
// graph nodes x ~15-18us; max kernel is only 42us). Phases kept
// byte-equivalent to the proven R16 kernels; partition re-expressed at
// 512 threads (EPT 16, in-place reg packing). Fallback to the discrete
// 4-dispatch path if cooperative launch is unsupported.

#define F_IN  5
#define F_HID 5
#define F_OUT 10

#define NBSHIFT 7                 // nodes per bucket = 128
#define NPB     (1 << NBSHIFT)    // 128
#define PBLK    1024              // discrete partition block size
#define CHUNK   8192              // edges per partition chunk
#define EPT     8                 // edges/thread, discrete partition (1024 thr)
#define BSTRIDE 9216              // bucket stride: mean 8184 + ~11 sigma
#define SBLK    512               // sortagg1 block size
#define SPT     18                // staged entries/thread = BSTRIDE/SBLK
#define LPN2    8                 // lanes per node in layer2
#define LBLK    256               // discrete layer2 block size
#define FBLK    512               // fused block size
#define EPTF    16                // edges/thread, fused partition (512 thr)

__device__ __forceinline__ float sigmoidf(float v) {
    return 1.0f / (1.0f + __expf(-v));
}

__device__ __forceinline__ uint4 pack_h5(const float* __restrict__ xr) {
    float4 a = *(const float4*)xr;
    float a4 = xr[4];
    uint4 o;
    o.x = (unsigned)__half_as_ushort(__float2half_rn(a.x)) |
          ((unsigned)__half_as_ushort(__float2half_rn(a.y)) << 16);
    o.y = (unsigned)__half_as_ushort(__float2half_rn(a.z)) |
          ((unsigned)__half_as_ushort(__float2half_rn(a.w)) << 16);
    o.z = (unsigned)__half_as_ushort(__float2half_rn(a4));
    o.w = 0;
    return o;
}

// ---------------------------------------------------------------------------
// Fused cooperative kernel: zero bcursor -> partition -> sortagg1 -> layer2
// ---------------------------------------------------------------------------
union SharedU {
    struct {                      // partition phase: 53,344 B
        int cnt[1024];
        int excl[1024];
        int adj[1024];
        int wsum[16];
        int buf[CHUNK];
        unsigned char dlow[CHUNK];
    } part;
    struct {                      // sortagg phase: 37,892 B
        int buf[BSTRIDE];
        int ncnt[NPB];
        int nst[NPB];
        int w0sum;
    } srt;
};

__global__ void __launch_bounds__(FBLK, 4)
fused(const float* __restrict__ x,
      const int* __restrict__ src, const int* __restrict__ dst,
      int* __restrict__ bcursor, int* __restrict__ packed,
      uint4* __restrict__ xh,
      const float* __restrict__ Ws1, const float* __restrict__ Wn1,
      const float* __restrict__ b1,
      uint4* __restrict__ hp, int2* __restrict__ sd,
      const float* __restrict__ Ws2, const float* __restrict__ Wn2,
      const float* __restrict__ b2,
      float* __restrict__ out,
      int E, int N, int NB, int NCHUNK, int NG2) {
    __shared__ SharedU sh;
    cg::grid_group gg = cg::this_grid();
    int t = threadIdx.x;
    int lane = t & 63, w = t >> 6;

    // ---- phase Z: zero the bucket cursors (replaces the memset dispatch) ----
    if (blockIdx.x == 0) { bcursor[t] = 0; bcursor[t + FBLK] = 0; }
    __threadfence();
    gg.sync();
    __threadfence();

    // ---- phase A: partition edges by dst>>7 (1 LDS cursor atomic/edge) ----
    for (int cc = blockIdx.x; cc < NCHUNK; cc += gridDim.x) {
        int base = cc * CHUNK;
        int end  = min(base + CHUNK, E);
        sh.part.cnt[t] = 0;
        sh.part.cnt[t + FBLK] = 0;
        // x -> fp16 conversion for this chunk's 128-node slice
        if (t < NPB) {
            int v = (cc << NBSHIFT) + t;
            if (v < N) xh[v] = pack_h5(x + (size_t)v * 5);
        }
        __syncthreads();
        // stage 16/thread: rounds r=0..3 -> i = base + r*2048 + t*4 (16B aligned)
        int sarr[EPTF], darr[EPTF];
        #pragma unroll
        for (int r = 0; r < 4; ++r) {
            int i = base + r * 2048 + t * 4;
            if (i + 4 <= end) {
                int4 sv = *(const int4*)(src + i);
                int4 dv = *(const int4*)(dst + i);
                sarr[r*4+0]=sv.x; sarr[r*4+1]=sv.y; sarr[r*4+2]=sv.z; sarr[r*4+3]=sv.w;
                darr[r*4+0]=dv.x; darr[r*4+1]=dv.y; darr[r*4+2]=dv.z; darr[r*4+3]=dv.w;
            } else {
                #pragma unroll
                for (int c = 0; c < 4; ++c) {
                    int i2 = i + c;
                    if (i2 < end) { sarr[r*4+c] = src[i2]; darr[r*4+c] = dst[i2]; }
                }
            }
        }
        // rank via single LDS cursor atomic; pack in place:
        //   sarr[j] := src | dlow<<17 ; darr[j] := b<<14 | p
        #pragma unroll
        for (int j = 0; j < EPTF; ++j) {
            int i = base + (j >> 2) * 2048 + t * 4 + (j & 3);
            if (i < end) {
                int d = darr[j];
                int b = d >> NBSHIFT;
                int p = atomicAdd(&sh.part.cnt[b], 1);
                sarr[j] |= (d & (NPB - 1)) << 17;
                darr[j] = (b << 14) | p;
            }
        }
        __syncthreads();
        // pairwise scan of 1024 bins with 512 threads
        int c0 = sh.part.cnt[2 * t], c1 = sh.part.cnt[2 * t + 1];
        int s = c0 + c1;
        int incl = s;
        #pragma unroll
        for (int off = 1; off < 64; off <<= 1) {
            int u = __shfl_up(incl, off, 64);
            if (lane >= off) incl += u;
        }
        if (lane == 63) sh.part.wsum[w] = incl;
        __syncthreads();
        if (t < 8) {
            int sv = sh.part.wsum[t];
            #pragma unroll
            for (int off = 1; off < 8; off <<= 1) {
                int u = __shfl_up(sv, off, 8);
                if (t >= off) sv += u;
            }
            sh.part.wsum[t] = sv;
        }
        __syncthreads();
        int wbase = (w > 0) ? sh.part.wsum[w - 1] : 0;
        int e0 = incl - s + wbase;
        sh.part.excl[2 * t]     = e0;
        sh.part.excl[2 * t + 1] = e0 + c0;
        __syncthreads();
        // reserve global space per bucket
        for (int bb = t; bb < NB; bb += FBLK) {
            int cb = sh.part.cnt[bb];
            int go = cb ? atomicAdd(&bcursor[bb], cb) : 0;
            sh.part.adj[bb] = bb * BSTRIDE + go - sh.part.excl[bb];
        }
        __syncthreads();
        // place from registers into LDS, bucket-grouped
        #pragma unroll
        for (int j = 0; j < EPTF; ++j) {
            int i = base + (j >> 2) * 2048 + t * 4 + (j & 3);
            if (i < end) {
                int b   = darr[j] >> 14;
                int pos = sh.part.excl[b] + (darr[j] & 0x3FFF);
                sh.part.buf[pos]  = (sarr[j] & 0x1FFFF) | (b << 17);
                sh.part.dlow[pos] = (unsigned char)(sarr[j] >> 17);
            }
        }
        __syncthreads();
        // write runs out (consecutive pos -> same bucket -> coalesced)
        int cval = end - base;
        for (int p = t; p < cval; p += FBLK) {
            int e = sh.part.buf[p];
            int b = e >> 17;
            packed[sh.part.adj[b] + p] = (e & 0x1FFFF) | ((int)sh.part.dlow[p] << 17);
        }
        __syncthreads();
    }
    __threadfence();
    gg.sync();
    __threadfence();

    // ---- phase B: per-bucket counting sort + layer-1 aggregation ----
    for (int bb = blockIdx.x; bb < NB; bb += gridDim.x) {
        int sb   = bb * BSTRIDE;
        int cntb = min(bcursor[bb], BSTRIDE);
        if (t < NPB) sh.srt.ncnt[t] = 0;
        __syncthreads();
        // stage: rounds r=0..3 -> i = r*2048 + t*4; tail i = 8192 + t*2
        int myv[SPT];
        #pragma unroll
        for (int r = 0; r < 4; ++r) {
            int i = r * 2048 + t * 4;
            if (i + 4 <= cntb) {
                int4 q = *(const int4*)(packed + sb + i);
                myv[r*4+0]=q.x; myv[r*4+1]=q.y; myv[r*4+2]=q.z; myv[r*4+3]=q.w;
            } else {
                #pragma unroll
                for (int c = 0; c < 4; ++c) {
                    int i2 = i + c;
                    myv[r*4+c] = (i2 < cntb) ? packed[sb + i2] : 0;
                }
            }
        }
        {
            int i = 8192 + t * 2;
            if (i + 2 <= cntb) {
                int2 q = *(const int2*)(packed + sb + i);
                myv[16] = q.x; myv[17] = q.y;
            } else {
                myv[16] = (i     < cntb) ? packed[sb + i]     : 0;
                myv[17] = (i + 1 < cntb) ? packed[sb + i + 1] : 0;
            }
        }
        // rank via single LDS cursor atomic
        short myp[SPT];
        #pragma unroll
        for (int j = 0; j < SPT; ++j) {
            int i = (j < 16) ? ((j >> 2) * 2048 + t * 4 + (j & 3)) : (8192 + t * 2 + (j - 16));
            if (i < cntb) {
                myp[j] = (short)atomicAdd(&sh.srt.ncnt[(myv[j] >> 17) & (NPB - 1)], 1);
            }
        }
        __syncthreads();
        // exclusive scan of 128 bins
        if (t < NPB) {
            int vv = sh.srt.ncnt[t];
            int incl = vv;
            #pragma unroll
            for (int off = 1; off < 64; off <<= 1) {
                int u = __shfl_up(incl, off, 64);
                if ((t & 63) >= off) incl += u;
            }
            if (t == 63) sh.srt.w0sum = incl;
            sh.srt.nst[t] = incl - vv;
        }
        __syncthreads();
        if (t >= 64 && t < NPB) sh.srt.nst[t] += sh.srt.w0sum;
        __syncthreads();
        if (t < NPB) {
            int node = (bb << NBSHIFT) + t;
            if (node < N) sd[node] = make_int2(sb + sh.srt.nst[t], sh.srt.ncnt[t]);
        }
        __syncthreads();
        // place sorted into LDS from registers
        #pragma unroll
        for (int j = 0; j < SPT; ++j) {
            int i = (j < 16) ? ((j >> 2) * 2048 + t * 4 + (j & 3)) : (8192 + t * 2 + (j - 16));
            if (i < cntb) {
                int e = myv[j];
                sh.srt.buf[sh.srt.nst[(e >> 17) & (NPB - 1)] + (int)myp[j]] = e;
            }
        }
        __syncthreads();
        // write sorted eidx back for layer2 (coalesced)
        for (int i = t; i < cntb; i += FBLK)
            packed[sb + i] = sh.srt.buf[i] & 0x1FFFF;
        // layer-1 aggregation from LDS, 4 lanes/node
        int sub = t & 3, ln = t >> 2;
        int node = (bb << NBSHIFT) + ln;
        float a0 = 0, a1 = 0, a2 = 0, a3 = 0, a4 = 0;
        int dg = 0;
        if (node < N) {
            int st = sh.srt.nst[ln];
            dg = sh.srt.ncnt[ln];
            for (int k = sub; k < dg; k += 4) {
                int u = sh.srt.buf[st + k] & 0x1FFFF;
                uint4 q = xh[u];
                float2 f01 = __half22float2(*(const __half2*)&q.x);
                float2 f23 = __half22float2(*(const __half2*)&q.y);
                float2 f45 = __half22float2(*(const __half2*)&q.z);
                a0 += f01.x; a1 += f01.y; a2 += f23.x; a3 += f23.y; a4 += f45.x;
            }
        }
        #pragma unroll
        for (int off = 2; off > 0; off >>= 1) {
            a0 += __shfl_down(a0, off, 4);
            a1 += __shfl_down(a1, off, 4);
            a2 += __shfl_down(a2, off, 4);
            a3 += __shfl_down(a3, off, 4);
            a4 += __shfl_down(a4, off, 4);
        }
        if (sub == 0 && node < N) {
            float rd = 1.0f / fmaxf((float)dg, 1.0f);
            float ni[F_IN] = { a0 * rd, a1 * rd, a2 * rd, a3 * rd, a4 * rd };
            uint4 qs = xh[node];
            float2 s01 = __half22float2(*(const __half2*)&qs.x);
            float2 s23 = __half22float2(*(const __half2*)&qs.y);
            float2 s45 = __half22float2(*(const __half2*)&qs.z);
            float xi[F_IN] = { s01.x, s01.y, s23.x, s23.y, s45.x };
            unsigned short hu[5];
            #pragma unroll
            for (int j = 0; j < F_HID; ++j) {
                float acc = b1[j];
                #pragma unroll
                for (int f = 0; f < F_IN; ++f)
                    acc += xi[f] * Ws1[f * F_HID + j] + ni[f] * Wn1[f * F_HID + j];
                hu[j] = __half_as_ushort(__float2half_rn(sigmoidf(acc)));
            }
            uint4 o;
            o.x = (unsigned)hu[0] | ((unsigned)hu[1] << 16);
            o.y = (unsigned)hu[2] | ((unsigned)hu[3] << 16);
            o.z = (unsigned)hu[4];
            o.w = 0;
            hp[node] = o;
        }
        __syncthreads();
    }
    __threadfence();
    gg.sync();
    __threadfence();

    // ---- phase C: layer 2, 8 lanes/node, contiguous k-ranges ----
    for (int g = blockIdx.x; g < NG2; g += gridDim.x) {
        int v   = (g << 6) + (t >> 3);
        int sub = t & (LPN2 - 1);
        float s0 = 0, s1 = 0, s2 = 0, s3 = 0, s4 = 0;
        int stv = 0, dg = 0;
        if (v < N) {
            int2 sdv = sd[v];
            stv = sdv.x; dg = sdv.y;
        }
        int len = (dg + LPN2 - 1) >> 3;
        int k0 = sub * len;
        int k1 = min(k0 + len, dg);
        int k = k0;
        for (; k + 4 <= k1; k += 4) {
            int4 qi;
            __builtin_memcpy(&qi, packed + stv + k, 16);
            #pragma unroll
            for (int c = 0; c < 4; ++c) {
                int u = (c == 0) ? qi.x : (c == 1) ? qi.y : (c == 2) ? qi.z : qi.w;
                uint4 q = hp[u];
                float2 f01 = __half22float2(*(const __half2*)&q.x);
                float2 f23 = __half22float2(*(const __half2*)&q.y);
                float2 f45 = __half22float2(*(const __half2*)&q.z);
                s0 += f01.x; s1 += f01.y; s2 += f23.x; s3 += f23.y; s4 += f45.x;
            }
        }
        for (; k < k1; ++k) {
            int u = packed[stv + k];
            uint4 q = hp[u];
            float2 f01 = __half22float2(*(const __half2*)&q.x);
            float2 f23 = __half22float2(*(const __half2*)&q.y);
            float2 f45 = __half22float2(*(const __half2*)&q.z);
            s0 += f01.x; s1 += f01.y; s2 += f23.x; s3 += f23.y; s4 += f45.x;
        }
        #pragma unroll
        for (int off = LPN2 / 2; off > 0; off >>= 1) {
            s0 += __shfl_down(s0, off, LPN2);
            s1 += __shfl_down(s1, off, LPN2);
            s2 += __shfl_down(s2, off, LPN2);
            s3 += __shfl_down(s3, off, LPN2);
            s4 += __shfl_down(s4, off, LPN2);
        }
        if (sub == 0 && v < N) {
            float rd = 1.0f / fmaxf((float)dg, 1.0f);
            float ni[F_HID] = { s0 * rd, s1 * rd, s2 * rd, s3 * rd, s4 * rd };
            uint4 q = hp[v];
            float2 f01 = __half22float2(*(const __half2*)&q.x);
            float2 f23 = __half22float2(*(const __half2*)&q.y);
            float2 f45 = __half22float2(*(const __half2*)&q.z);
            float hi[F_HID] = { f01.x, f01.y, f23.x, f23.y, f45.x };
            #pragma unroll
            for (int j = 0; j < F_OUT; ++j) {
                float acc = b2[j];
                #pragma unroll
                for (int f = 0; f < F_HID; ++f)
                    acc += hi[f] * Ws2[f * F_OUT + j] + ni[f] * Wn2[f * F_OUT + j];
                out[(size_t)v * F_OUT + j] = sigmoidf(acc);
            }
        }
    }
}

// ---------------------------------------------------------------------------
// Discrete fallback path (R16 kernels, unchanged) — used only if cooperative
// launch is unavailable or rejected by the runtime/graph capture.
// ---------------------------------------------------------------------------
__global__ void partition(const float* __restrict__ x,
                          const int* __restrict__ src, const int* __restrict__ dst,
                          int* __restrict__ bcursor, int* __restrict__ packed,
                          uint4* __restrict__ xh, int E, int N, int NB) {
    __shared__ int cnt[PBLK], excl[PBLK], adj[PBLK];
    __shared__ int wsum[16];
    __shared__ int buf[CHUNK];
    __shared__ unsigned char dlow[CHUNK];
    int t = threadIdx.x;
    int lane = t & 63, w = t >> 6;
    if (t < NPB) {
        int v = (blockIdx.x << NBSHIFT) + t;
        if (v < N) xh[v] = pack_h5(x + (size_t)v * 5);
    }
    cnt[t] = 0;
    __syncthreads();
    int base = blockIdx.x * CHUNK;
    int end  = min(base + CHUNK, E);
    int sarr[EPT], darr[EPT];
    #pragma unroll
    for (int r = 0; r < 2; ++r) {
        int i = base + r * 4096 + t * 4;
        if (i + 4 <= end) {
            int4 sv = *(const int4*)(src + i);
            int4 dv = *(const int4*)(dst + i);
            sarr[r*4+0]=sv.x; sarr[r*4+1]=sv.y; sarr[r*4+2]=sv.z; sarr[r*4+3]=sv.w;
            darr[r*4+0]=dv.x; darr[r*4+1]=dv.y; darr[r*4+2]=dv.z; darr[r*4+3]=dv.w;
        } else {
            #pragma unroll
            for (int c = 0; c < 4; ++c) {
                int i2 = i + c;
                if (i2 < end) { sarr[r*4+c] = src[i2]; darr[r*4+c] = dst[i2]; }
            }
        }
    }
    int esd[EPT], ebp[EPT];
    #pragma unroll
    for (int j = 0; j < EPT; ++j) {
        int i = base + (j >> 2) * 4096 + t * 4 + (j & 3);
        if (i < end) {
            int sv = sarr[j], d = darr[j];
            int b  = d >> NBSHIFT;
            int p  = atomicAdd(&cnt[b], 1);
            esd[j] = sv | ((d & (NPB - 1)) << 17);
            ebp[j] = (b << 14) | p;
        }
    }
    __syncthreads();
    int v = cnt[t];
    int incl = v;
    #pragma unroll
    for (int off = 1; off < 64; off <<= 1) {
        int u = __shfl_up(incl, off, 64);
        if (lane >= off) incl += u;
    }
    if (lane == 63) wsum[w] = incl;
    __syncthreads();
    if (t < 16) {
        int s = wsum[t];
        #pragma unroll
        for (int off = 1; off < 16; off <<= 1) {
            int u = __shfl_up(s, off, 16);
            if (t >= off) s += u;
        }
        wsum[t] = s;
    }
    __syncthreads();
    int wbase = (w > 0) ? wsum[w - 1] : 0;
    excl[t] = incl - v + wbase;
    __syncthreads();
    if (t < NB) {
        int cb = cnt[t];
        int go = cb ? atomicAdd(&bcursor[t], cb) : 0;
        adj[t] = t * BSTRIDE + go - excl[t];
    }
    __syncthreads();
    #pragma unroll
    for (int j = 0; j < EPT; ++j) {
        int i = base + (j >> 2) * 4096 + t * 4 + (j & 3);
        if (i < end) {
            int b   = ebp[j] >> 14;
            int pos = excl[b] + (ebp[j] & 0x3FFF);
            buf[pos]  = (esd[j] & 0x1FFFF) | (b << 17);
            dlow[pos] = (unsigned char)(esd[j] >> 17);
        }
    }
    __syncthreads();
    int cval = end - base;
    for (int p = t; p < cval; p += PBLK) {
        int e = buf[p];
        int b = e >> 17;
        packed[adj[b] + p] = (e & 0x1FFFF) | ((int)dlow[p] << 17);
    }
}

__global__ void __launch_bounds__(SBLK, 8)
sortagg1(const uint4* __restrict__ xh, int* __restrict__ packed,
         const int* __restrict__ bcursor,
         const float* __restrict__ Ws, const float* __restrict__ Wn,
         const float* __restrict__ bias,
         uint4* __restrict__ hp, int2* __restrict__ sd, int N) {
    __shared__ int buf[BSTRIDE];
    __shared__ int ncnt[NPB], nst[NPB];
    __shared__ int w0sum;
    int b = blockIdx.x, t = threadIdx.x;
    int s0  = b * BSTRIDE;
    int cnt = min(bcursor[b], BSTRIDE);
    if (t < NPB) ncnt[t] = 0;
    __syncthreads();
    int myv[SPT];
    #pragma unroll
    for (int r = 0; r < 4; ++r) {
        int i = r * 2048 + t * 4;
        if (i + 4 <= cnt) {
            int4 q = *(const int4*)(packed + s0 + i);
            myv[r*4+0]=q.x; myv[r*4+1]=q.y; myv[r*4+2]=q.z; myv[r*4+3]=q.w;
        } else {
            #pragma unroll
            for (int c = 0; c < 4; ++c) {
                int i2 = i + c;
                myv[r*4+c] = (i2 < cnt) ? packed[s0 + i2] : 0;
            }
        }
    }
    {
        int i = 8192 + t * 2;
        if (i + 2 <= cnt) {
            int2 q = *(const int2*)(packed + s0 + i);
            myv[16] = q.x; myv[17] = q.y;
        } else {
            myv[16] = (i     < cnt) ? packed[s0 + i]     : 0;
            myv[17] = (i + 1 < cnt) ? packed[s0 + i + 1] : 0;
        }
    }
    short myp[SPT];
    #pragma unroll
    for (int j = 0; j < SPT; ++j) {
        int i = (j < 16) ? ((j >> 2) * 2048 + t * 4 + (j & 3)) : (8192 + t * 2 + (j - 16));
        if (i < cnt) {
            myp[j] = (short)atomicAdd(&ncnt[(myv[j] >> 17) & (NPB - 1)], 1);
        }
    }
    __syncthreads();
    if (t < NPB) {
        int lane = t & 63;
        int vv = ncnt[t];
        int incl = vv;
        #pragma unroll
        for (int off = 1; off < 64; off <<= 1) {
            int u = __shfl_up(incl, off, 64);
            if (lane >= off) incl += u;
        }
        if (t == 63) w0sum = incl;
        nst[t] = incl - vv;
    }
    __syncthreads();
    if (t >= 64 && t < NPB) nst[t] += w0sum;
    __syncthreads();
    if (t < NPB) {
        int node = (b << NBSHIFT) + t;
        if (node < N) sd[node] = make_int2(s0 + nst[t], ncnt[t]);
    }
    __syncthreads();
    #pragma unroll
    for (int j = 0; j < SPT; ++j) {
        int i = (j < 16) ? ((j >> 2) * 2048 + t * 4 + (j & 3)) : (8192 + t * 2 + (j - 16));
        if (i < cnt) {
            int e = myv[j];
            buf[nst[(e >> 17) & (NPB - 1)] + (int)myp[j]] = e;
        }
    }
    __syncthreads();
    for (int i = t; i < cnt; i += SBLK)
        packed[s0 + i] = buf[i] & 0x1FFFF;
    int sub = t & 3, ln = t >> 2;
    int node = (b << NBSHIFT) + ln;
    float a0 = 0, a1 = 0, a2 = 0, a3 = 0, a4 = 0;
    int dg = 0;
    if (node < N) {
        int st = nst[ln];
        dg = ncnt[ln];
        for (int k = sub; k < dg; k += 4) {
            int u = buf[st + k] & 0x1FFFF;
            uint4 q = xh[u];
            float2 f01 = __half22float2(*(const __half2*)&q.x);
            float2 f23 = __half22float2(*(const __half2*)&q.y);
            float2 f45 = __half22float2(*(const __half2*)&q.z);
            a0 += f01.x; a1 += f01.y; a2 += f23.x; a3 += f23.y; a4 += f45.x;
        }
    }
    #pragma unroll
    for (int off = 2; off > 0; off >>= 1) {
        a0 += __shfl_down(a0, off, 4);
        a1 += __shfl_down(a1, off, 4);
        a2 += __shfl_down(a2, off, 4);
        a3 += __shfl_down(a3, off, 4);
        a4 += __shfl_down(a4, off, 4);
    }
    if (sub != 0 || node >= N) return;
    float rd = 1.0f / fmaxf((float)dg, 1.0f);
    float ni[F_IN] = { a0 * rd, a1 * rd, a2 * rd, a3 * rd, a4 * rd };
    uint4 qs = xh[node];
    float2 s01 = __half22float2(*(const __half2*)&qs.x);
    float2 s23 = __half22float2(*(const __half2*)&qs.y);
    float2 s45 = __half22float2(*(const __half2*)&qs.z);
    float xi[F_IN] = { s01.x, s01.y, s23.x, s23.y, s45.x };
    unsigned short hu[5];
    #pragma unroll
    for (int j = 0; j < F_HID; ++j) {
        float acc = bias[j];
        #pragma unroll
        for (int f = 0; f < F_IN; ++f)
            acc += xi[f] * Ws[f * F_HID + j] + ni[f] * Wn[f * F_HID + j];
        hu[j] = __half_as_ushort(__float2half_rn(sigmoidf(acc)));
    }
    uint4 o;
    o.x = (unsigned)hu[0] | ((unsigned)hu[1] << 16);
    o.y = (unsigned)hu[2] | ((unsigned)hu[3] << 16);
    o.z = (unsigned)hu[4];
    o.w = 0;
    hp[node] = o;
}

__global__ void layer2(const uint4* __restrict__ hp, const int* __restrict__ eidx,
                       const int2* __restrict__ sd,
                       const float* __restrict__ Ws, const float* __restrict__ Wn,
                       const float* __restrict__ b,
                       float* __restrict__ out, int N) {
    int tid = blockIdx.x * blockDim.x + threadIdx.x;
    int v   = tid >> 3;
    int sub = threadIdx.x & (LPN2 - 1);
    if (v >= N) return;
    int2 sdv = sd[v];
    int st = sdv.x, dg = sdv.y;
    int len = (dg + LPN2 - 1) >> 3;
    int k0 = sub * len;
    int k1 = min(k0 + len, dg);
    float s0 = 0, s1 = 0, s2 = 0, s3 = 0, s4 = 0;
    int k = k0;
    for (; k + 4 <= k1; k += 4) {
        int4 qi;
        __builtin_memcpy(&qi, eidx + st + k, 16);
        #pragma unroll
        for (int c = 0; c < 4; ++c) {
            int u = (c == 0) ? qi.x : (c == 1) ? qi.y : (c == 2) ? qi.z : qi.w;
            uint4 q = hp[u];
            float2 f01 = __half22float2(*(const __half2*)&q.x);
            float2 f23 = __half22float2(*(const __half2*)&q.y);
            float2 f45 = __half22float2(*(const __half2*)&q.z);
            s0 += f01.x; s1 += f01.y; s2 += f23.x; s3 += f23.y; s4 += f45.x;
        }
    }
    for (; k < k1; ++k) {
        int u = eidx[st + k];
        uint4 q = hp[u];
        float2 f01 = __half22float2(*(const __half2*)&q.x);
        float2 f23 = __half22float2(*(const __half2*)&q.y);
        float2 f45 = __half22float2(*(const __half2*)&q.z);
        s0 += f01.x; s1 += f01.y; s2 += f23.x; s3 += f23.y; s4 += f45.x;
    }
    #pragma unroll
    for (int off = LPN2 / 2; off > 0; off >>= 1) {
        s0 += __shfl_down(s0, off, LPN2);
        s1 += __shfl_down(s1, off, LPN2);
        s2 += __shfl_down(s2, off, LPN2);
        s3 += __shfl_down(s3, off, LPN2);
        s4 += __shfl_down(s4, off, LPN2);
    }
    if (sub != 0) return;
    float rd = 1.0f / fmaxf((float)dg, 1.0f);
    float ni[F_HID] = { s0 * rd, s1 * rd, s2 * rd, s3 * rd, s4 * rd };
    uint4 q = hp[v];
    float2 f01 = __half22float2(*(const __half2*)&q.x);
    float2 f23 = __half22float2(*(const __half2*)&q.y);
    float2 f45 = __half22float2(*(const __half2*)&q.z);
    float hi[F_HID] = { f01.x, f01.y, f23.x, f23.y, f45.x };
    #pragma unroll
    for (int j = 0; j < F_OUT; ++j) {
        float acc = b[j];
        #pragma unroll
        for (int f = 0; f < F_HID; ++f)
            acc += hi[f] * Ws[f * F_OUT + j] + ni[f] * Wn[f * F_OUT + j];
        out[(size_t)v * F_OUT + j] = sigmoidf(acc);
    }
}

extern "C" void kernel_launch(void* const* d_in, const int* in_sizes, int n_in,
                              void* d_out, int out_size, void* d_ws, size_t ws_size,
                              hipStream_t stream) {
    const float* x   = (const float*)d_in[0];
    const int*   src = (const int*)d_in[1];
    const int*   dst = (const int*)d_in[2];
    const float* Ws1 = (const float*)d_in[3];
    const float* Wn1 = (const float*)d_in[4];
    const float* b1  = (const float*)d_in[5];
    const float* Ws2 = (const float*)d_in[6];
    const float* Wn2 = (const float*)d_in[7];
    const float* b2  = (const float*)d_in[8];
    float* out = (float*)d_out;

    const int N  = in_sizes[0] / F_IN;        // 100000
    const int E  = in_sizes[1];               // 6400000
    const int NB = (N + NPB - 1) >> NBSHIFT;  // 782
    const int NCHUNK = (E + CHUNK - 1) / CHUNK;  // 782
    const int NG2 = (N + 63) >> 6;            // 1563

    // workspace (4B units):
    // bcursor[1024] | xh[4N] | sd[2N] | packed[NB*BSTRIDE] | hp[4N]
    int*   bcursor = (int*)d_ws;
    uint4* xh      = (uint4*)(bcursor + 1024);
    int2*  sd      = (int2*)(xh + N);
    int*   packed  = (int*)(sd + N);
    uint4* hp      = (uint4*)(packed + (size_t)NB * BSTRIDE);

    // one-time host-side occupancy/capability probe (capture-safe; cached)
    static int coop_blocks = -2;
    if (coop_blocks == -2) {
        int dev = 0; (void)hipGetDevice(&dev);
        int can = 0, ncu = 0, bpc = 0;
        (void)hipDeviceGetAttribute(&can, hipDeviceAttributeCooperativeLaunch, dev);
        (void)hipDeviceGetAttribute(&ncu, hipDeviceAttributeMultiprocessorCount, dev);
        hipError_t oe = hipOccupancyMaxActiveBlocksPerMultiprocessor(&bpc, fused, FBLK, 0);
        coop_blocks = (can && ncu > 0 && oe == hipSuccess && bpc > 0) ? bpc * ncu : 0;
    }

    if (coop_blocks > 0) {
        int grid = coop_blocks;
        if (grid > NG2) grid = NG2;  // no useful parallelism beyond layer2's groups
        int e_ = E, n_ = N, nb_ = NB, nc_ = NCHUNK, ng_ = NG2;
        void* args[] = {
            (void*)&x, (void*)&src, (void*)&dst, (void*)&bcursor, (void*)&packed,
            (void*)&xh, (void*)&Ws1, (void*)&Wn1, (void*)&b1, (void*)&hp, (void*)&sd,
            (void*)&Ws2, (void*)&Wn2, (void*)&b2, (void*)&out,
            (void*)&e_, (void*)&n_, (void*)&nb_, (void*)&nc_, (void*)&ng_
        };
        hipError_t err = hipLaunchCooperativeKernel((const void*)fused, dim3(grid),
                                                    dim3(FBLK), args, 0, stream);
        if (err == hipSuccess) return;
        coop_blocks = 0;  // fall through to the discrete path
    }

    const int ablocks = (E + CHUNK - 1) / CHUNK;              // 782
    const int lgrid   = ((size_t)N * LPN2 + LBLK - 1) / LBLK; // 3125

    (void)hipMemsetAsync(bcursor, 0, 1024 * sizeof(int), stream);
    partition<<<ablocks, PBLK, 0, stream>>>(x, src, dst, bcursor, packed, xh, E, N, NB);
    sortagg1<<<NB, SBLK, 0, stream>>>(xh, packed, bcursor, Ws1, Wn1, b1, hp, sd, N);
    layer2<<<lgrid, LBLK, 0, stream>>>(hp, packed, sd, Ws2, Wn2, b2, out, N);
}

// Round 2
// 201.896 us; speedup vs baseline: 2.5836x; 2.5836x over previous
//
#include <hip/hip_runtime.h>
#include <hip/hip_fp16.h>
#include <math.h>

// GraphSAGE mean, 2 layers. F_IN=5, F_HID=5, F_OUT=10.
// R18 = R16 (discrete 4-dispatch path, known 200us) + sortagg1 latency fixes:
//  - layer-1 aggregation gather unrolled x4 (4 xh gathers in flight/lane;
//    was 1 -> latency-bound on ~200-400cy L2 hits).
//  - sorted-eidx writeback vectorized to int4 stores (18 dwords -> 4-5 int4).
// R17 post-mortem: cooperative fused kernel = 709us; cg grid.sync costs
// ~150+us each on this runtime (spin-barrier, cross-XCD atomic storm).
// Grid-wide fusion is strictly worse than the ~15us dispatch gaps. Reverted.

#define F_IN  5
#define F_HID 5
#define F_OUT 10

#define NBSHIFT 7                 // nodes per bucket = 128
#define NPB     (1 << NBSHIFT)    // 128
#define PBLK    1024              // partition block size
#define CHUNK   8192              // edges per partition block -> run len ~10.5
#define EPT     8                 // edges per thread in partition
#define BSTRIDE 9216              // bucket stride: mean 8192 + ~11 sigma; 18*512
#define SBLK    512               // sortagg1 block size (4 lanes/node * 128)
#define SPT     18                // staged entries/thread = BSTRIDE/SBLK
#define LPN2    8                 // lanes per node in layer2
#define LBLK    256               // layer2 block size

__device__ __forceinline__ float sigmoidf(float v) {
    return 1.0f / (1.0f + __expf(-v));
}

__device__ __forceinline__ uint4 pack_h5(const float* __restrict__ xr) {
    float4 a = *(const float4*)xr;
    float a4 = xr[4];
    uint4 o;
    o.x = (unsigned)__half_as_ushort(__float2half_rn(a.x)) |
          ((unsigned)__half_as_ushort(__float2half_rn(a.y)) << 16);
    o.y = (unsigned)__half_as_ushort(__float2half_rn(a.z)) |
          ((unsigned)__half_as_ushort(__float2half_rn(a.w)) << 16);
    o.z = (unsigned)__half_as_ushort(__float2half_rn(a4));
    o.w = 0;
    return o;
}

__device__ __forceinline__ void acc5(uint4 q, float& a0, float& a1, float& a2,
                                     float& a3, float& a4) {
    float2 f01 = __half22float2(*(const __half2*)&q.x);
    float2 f23 = __half22float2(*(const __half2*)&q.y);
    float2 f45 = __half22float2(*(const __half2*)&q.z);
    a0 += f01.x; a1 += f01.y; a2 += f23.x; a3 += f23.y; a4 += f45.x;
}

// ---- K1: partition edges by dst>>7 (cursor-first, 1 LDS atomic/edge);
//      each block also converts its 128-node slice of x to fp16 uint4 rows ----
__global__ void partition(const float* __restrict__ x,
                          const int* __restrict__ src, const int* __restrict__ dst,
                          int* __restrict__ bcursor, int* __restrict__ packed,
                          uint4* __restrict__ xh, int E, int N, int NB) {
    __shared__ int cnt[PBLK], excl[PBLK], adj[PBLK];
    __shared__ int wsum[16];
    __shared__ int buf[CHUNK];
    __shared__ unsigned char dlow[CHUNK];
    int t = threadIdx.x;
    int lane = t & 63, w = t >> 6;
    // x -> fp16 conversion for this block's node slice
    if (t < NPB) {
        int v = (blockIdx.x << NBSHIFT) + t;
        if (v < N) xh[v] = pack_h5(x + (size_t)v * 5);
    }
    cnt[t] = 0;
    __syncthreads();
    int base = blockIdx.x * CHUNK;
    int end  = min(base + CHUNK, E);
    // phase 0: vector-stage src/dst: rounds r=0,1 -> i = base + r*4096 + t*4 (16B aligned)
    int sarr[EPT], darr[EPT];
    #pragma unroll
    for (int r = 0; r < 2; ++r) {
        int i = base + r * 4096 + t * 4;
        if (i + 4 <= end) {
            int4 sv = *(const int4*)(src + i);
            int4 dv = *(const int4*)(dst + i);
            sarr[r*4+0]=sv.x; sarr[r*4+1]=sv.y; sarr[r*4+2]=sv.z; sarr[r*4+3]=sv.w;
            darr[r*4+0]=dv.x; darr[r*4+1]=dv.y; darr[r*4+2]=dv.z; darr[r*4+3]=dv.w;
        } else {
            #pragma unroll
            for (int c = 0; c < 4; ++c) {
                int i2 = i + c;
                if (i2 < end) { sarr[r*4+c] = src[i2]; darr[r*4+c] = dst[i2]; }
            }
        }
    }
    // phase 1: rank via single LDS cursor atomic
    int esd[EPT];   // src | dlow<<17
    int ebp[EPT];   // b<<14 | p   (p < 8192)
    #pragma unroll
    for (int j = 0; j < EPT; ++j) {
        int i = base + (j >> 2) * 4096 + t * 4 + (j & 3);
        if (i < end) {
            int sv = sarr[j], d = darr[j];
            int b  = d >> NBSHIFT;
            int p  = atomicAdd(&cnt[b], 1);
            esd[j] = sv | ((d & (NPB - 1)) << 17);
            ebp[j] = (b << 14) | p;
        }
    }
    __syncthreads();
    // wave-shuffle inclusive scan of cnt[0..PBLK)
    int v = cnt[t];
    int incl = v;
    #pragma unroll
    for (int off = 1; off < 64; off <<= 1) {
        int u = __shfl_up(incl, off, 64);
        if (lane >= off) incl += u;
    }
    if (lane == 63) wsum[w] = incl;
    __syncthreads();
    if (t < 16) {
        int s = wsum[t];
        #pragma unroll
        for (int off = 1; off < 16; off <<= 1) {
            int u = __shfl_up(s, off, 16);
            if (t >= off) s += u;
        }
        wsum[t] = s;
    }
    __syncthreads();
    int wbase = (w > 0) ? wsum[w - 1] : 0;
    excl[t] = incl - v + wbase;
    __syncthreads();
    // reserve global space per bucket (bcursor zero-based; region = b*BSTRIDE)
    if (t < NB) {
        int cb = cnt[t];
        int go = cb ? atomicAdd(&bcursor[t], cb) : 0;
        adj[t] = t * BSTRIDE + go - excl[t];
    }
    __syncthreads();
    // phase 2: place from registers into LDS, bucket-grouped (plain writes)
    #pragma unroll
    for (int j = 0; j < EPT; ++j) {
        int i = base + (j >> 2) * 4096 + t * 4 + (j & 3);
        if (i < end) {
            int b   = ebp[j] >> 14;
            int pos = excl[b] + (ebp[j] & 0x3FFF);
            buf[pos]  = (esd[j] & 0x1FFFF) | (b << 17);
            dlow[pos] = (unsigned char)(esd[j] >> 17);
        }
    }
    __syncthreads();
    // phase 3: write runs out (consecutive pos -> same bucket -> coalesced)
    int cval = end - base;
    for (int p = t; p < cval; p += PBLK) {
        int e = buf[p];
        int b = e >> 17;
        packed[adj[b] + p] = (e & 0x1FFFF) | ((int)dlow[p] << 17);
    }
}

// ---- K2: per-bucket counting sort (cursor-first, vector-staged) + layer-1 ----
__global__ void __launch_bounds__(SBLK, 8)
sortagg1(const uint4* __restrict__ xh, int* __restrict__ packed,
         const int* __restrict__ bcursor,
         const float* __restrict__ Ws, const float* __restrict__ Wn,
         const float* __restrict__ bias,
         uint4* __restrict__ hp, int2* __restrict__ sd, int N) {
    __shared__ int buf[BSTRIDE];
    __shared__ int ncnt[NPB], nst[NPB];
    __shared__ int w0sum;
    int b = blockIdx.x, t = threadIdx.x;
    int s0  = b * BSTRIDE;
    int cnt = min(bcursor[b], BSTRIDE);
    if (t < NPB) ncnt[t] = 0;
    __syncthreads();
    // phase 0: vector-stage packed: rounds r=0..3 -> i = r*2048 + t*4 (16B aligned),
    // then tail round i = 8192 + t*2 (8B aligned). Total 18/thread.
    int myv[SPT];
    #pragma unroll
    for (int r = 0; r < 4; ++r) {
        int i = r * 2048 + t * 4;
        if (i + 4 <= cnt) {
            int4 q = *(const int4*)(packed + s0 + i);
            myv[r*4+0]=q.x; myv[r*4+1]=q.y; myv[r*4+2]=q.z; myv[r*4+3]=q.w;
        } else {
            #pragma unroll
            for (int c = 0; c < 4; ++c) {
                int i2 = i + c;
                myv[r*4+c] = (i2 < cnt) ? packed[s0 + i2] : 0;
            }
        }
    }
    {
        int i = 8192 + t * 2;
        if (i + 2 <= cnt) {
            int2 q = *(const int2*)(packed + s0 + i);
            myv[16] = q.x; myv[17] = q.y;
        } else {
            myv[16] = (i     < cnt) ? packed[s0 + i]     : 0;
            myv[17] = (i + 1 < cnt) ? packed[s0 + i + 1] : 0;
        }
    }
    // phase 1: rank via single LDS cursor atomic
    short myp[SPT];
    #pragma unroll
    for (int j = 0; j < SPT; ++j) {
        int i = (j < 16) ? ((j >> 2) * 2048 + t * 4 + (j & 3)) : (8192 + t * 2 + (j - 16));
        if (i < cnt) {
            myp[j] = (short)atomicAdd(&ncnt[(myv[j] >> 17) & (NPB - 1)], 1);
        }
    }
    __syncthreads();
    // wave-shuffle exclusive scan of 128 bins
    if (t < NPB) {
        int lane = t & 63;
        int vv = ncnt[t];
        int incl = vv;
        #pragma unroll
        for (int off = 1; off < 64; off <<= 1) {
            int u = __shfl_up(incl, off, 64);
            if (lane >= off) incl += u;
        }
        if (t == 63) w0sum = incl;
        nst[t] = incl - vv;
    }
    __syncthreads();
    if (t >= 64 && t < NPB) nst[t] += w0sum;
    __syncthreads();
    if (t < NPB) {
        int node = (b << NBSHIFT) + t;
        if (node < N) sd[node] = make_int2(s0 + nst[t], ncnt[t]);
    }
    __syncthreads();
    // phase 2: place sorted into LDS from registers (plain writes)
    #pragma unroll
    for (int j = 0; j < SPT; ++j) {
        int i = (j < 16) ? ((j >> 2) * 2048 + t * 4 + (j & 3)) : (8192 + t * 2 + (j - 16));
        if (i < cnt) {
            int e = myv[j];
            buf[nst[(e >> 17) & (NPB - 1)] + (int)myp[j]] = e;
        }
    }
    __syncthreads();
    // phase 3: write sorted eidx back for layer2 — int4 stores (16B aligned:
    // s0 = b*9216, i multiple of 4)
    for (int i = t * 4; i + 4 <= cnt; i += SBLK * 4) {
        int4 o = make_int4(buf[i] & 0x1FFFF, buf[i + 1] & 0x1FFFF,
                           buf[i + 2] & 0x1FFFF, buf[i + 3] & 0x1FFFF);
        *(int4*)(packed + s0 + i) = o;
    }
    {
        int tb = cnt & ~3;
        int i = tb + t;
        if (i < cnt) packed[s0 + i] = buf[i] & 0x1FFFF;
    }
    // phase 4: layer-1 aggregation from LDS, 4 lanes/node, x4-unrolled gathers
    int sub = t & 3, ln = t >> 2;          // ln in [0,128)
    int node = (b << NBSHIFT) + ln;
    float a0 = 0, a1 = 0, a2 = 0, a3 = 0, a4 = 0;
    int dg = 0;
    if (node < N) {
        int st = nst[ln];
        dg = ncnt[ln];
        int k = sub;
        for (; k + 12 < dg; k += 16) {
            int u0 = buf[st + k]      & 0x1FFFF;
            int u1 = buf[st + k + 4]  & 0x1FFFF;
            int u2 = buf[st + k + 8]  & 0x1FFFF;
            int u3 = buf[st + k + 12] & 0x1FFFF;
            uint4 q0 = xh[u0];
            uint4 q1 = xh[u1];
            uint4 q2 = xh[u2];
            uint4 q3 = xh[u3];
            acc5(q0, a0, a1, a2, a3, a4);
            acc5(q1, a0, a1, a2, a3, a4);
            acc5(q2, a0, a1, a2, a3, a4);
            acc5(q3, a0, a1, a2, a3, a4);
        }
        for (; k < dg; k += 4) {
            int u = buf[st + k] & 0x1FFFF;
            acc5(xh[u], a0, a1, a2, a3, a4);
        }
    }
    #pragma unroll
    for (int off = 2; off > 0; off >>= 1) {
        a0 += __shfl_down(a0, off, 4);
        a1 += __shfl_down(a1, off, 4);
        a2 += __shfl_down(a2, off, 4);
        a3 += __shfl_down(a3, off, 4);
        a4 += __shfl_down(a4, off, 4);
    }
    if (sub != 0 || node >= N) return;
    float rd = 1.0f / fmaxf((float)dg, 1.0f);
    float ni[F_IN] = { a0 * rd, a1 * rd, a2 * rd, a3 * rd, a4 * rd };
    uint4 qs = xh[node];
    float2 s01 = __half22float2(*(const __half2*)&qs.x);
    float2 s23 = __half22float2(*(const __half2*)&qs.y);
    float2 s45 = __half22float2(*(const __half2*)&qs.z);
    float xi[F_IN] = { s01.x, s01.y, s23.x, s23.y, s45.x };
    unsigned short hu[5];
    #pragma unroll
    for (int j = 0; j < F_HID; ++j) {
        float acc = bias[j];
        #pragma unroll
        for (int f = 0; f < F_IN; ++f)
            acc += xi[f] * Ws[f * F_HID + j] + ni[f] * Wn[f * F_HID + j];
        hu[j] = __half_as_ushort(__float2half_rn(sigmoidf(acc)));
    }
    uint4 o;
    o.x = (unsigned)hu[0] | ((unsigned)hu[1] << 16);
    o.y = (unsigned)hu[2] | ((unsigned)hu[3] << 16);
    o.z = (unsigned)hu[4];
    o.w = 0;
    hp[node] = o;
}

// ---- K3: layer 2, 8 lanes/node, contiguous k-ranges + int4 index loads ----
__global__ void layer2(const uint4* __restrict__ hp, const int* __restrict__ eidx,
                       const int2* __restrict__ sd,
                       const float* __restrict__ Ws, const float* __restrict__ Wn,
                       const float* __restrict__ b,
                       float* __restrict__ out, int N) {
    int tid = blockIdx.x * blockDim.x + threadIdx.x;
    int v   = tid >> 3;
    int sub = threadIdx.x & (LPN2 - 1);
    if (v >= N) return;
    int2 sdv = sd[v];
    int st = sdv.x, dg = sdv.y;
    int len = (dg + LPN2 - 1) >> 3;
    int k0 = sub * len;
    int k1 = min(k0 + len, dg);
    float s0 = 0, s1 = 0, s2 = 0, s3 = 0, s4 = 0;
    int k = k0;
    for (; k + 4 <= k1; k += 4) {
        int4 qi;
        __builtin_memcpy(&qi, eidx + st + k, 16);
        uint4 q0 = hp[qi.x];
        uint4 q1 = hp[qi.y];
        uint4 q2 = hp[qi.z];
        uint4 q3 = hp[qi.w];
        acc5(q0, s0, s1, s2, s3, s4);
        acc5(q1, s0, s1, s2, s3, s4);
        acc5(q2, s0, s1, s2, s3, s4);
        acc5(q3, s0, s1, s2, s3, s4);
    }
    for (; k < k1; ++k) {
        int u = eidx[st + k];
        acc5(hp[u], s0, s1, s2, s3, s4);
    }
    #pragma unroll
    for (int off = LPN2 / 2; off > 0; off >>= 1) {
        s0 += __shfl_down(s0, off, LPN2);
        s1 += __shfl_down(s1, off, LPN2);
        s2 += __shfl_down(s2, off, LPN2);
        s3 += __shfl_down(s3, off, LPN2);
        s4 += __shfl_down(s4, off, LPN2);
    }
    if (sub != 0) return;
    float rd = 1.0f / fmaxf((float)dg, 1.0f);
    float ni[F_HID] = { s0 * rd, s1 * rd, s2 * rd, s3 * rd, s4 * rd };
    uint4 q = hp[v];
    float2 f01 = __half22float2(*(const __half2*)&q.x);
    float2 f23 = __half22float2(*(const __half2*)&q.y);
    float2 f45 = __half22float2(*(const __half2*)&q.z);
    float hi[F_HID] = { f01.x, f01.y, f23.x, f23.y, f45.x };
    #pragma unroll
    for (int j = 0; j < F_OUT; ++j) {
        float acc = b[j];
        #pragma unroll
        for (int f = 0; f < F_HID; ++f)
            acc += hi[f] * Ws[f * F_OUT + j] + ni[f] * Wn[f * F_OUT + j];
        out[(size_t)v * F_OUT + j] = sigmoidf(acc);
    }
}

extern "C" void kernel_launch(void* const* d_in, const int* in_sizes, int n_in,
                              void* d_out, int out_size, void* d_ws, size_t ws_size,
                              hipStream_t stream) {
    const float* x   = (const float*)d_in[0];
    const int*   src = (const int*)d_in[1];
    const int*   dst = (const int*)d_in[2];
    const float* Ws1 = (const float*)d_in[3];
    const float* Wn1 = (const float*)d_in[4];
    const float* b1  = (const float*)d_in[5];
    const float* Ws2 = (const float*)d_in[6];
    const float* Wn2 = (const float*)d_in[7];
    const float* b2  = (const float*)d_in[8];
    float* out = (float*)d_out;

    const int N  = in_sizes[0] / F_IN;        // 100000
    const int E  = in_sizes[1];               // 6400000
    const int NB = (N + NPB - 1) >> NBSHIFT;  // 782

    // workspace (4B units):
    // bcursor[1024] (zero-based) | xh[4N] | sd[2N] | packed[NB*BSTRIDE] | hp[4N]
    int*   bcursor = (int*)d_ws;
    uint4* xh      = (uint4*)(bcursor + 1024);
    int2*  sd      = (int2*)(xh + N);
    int*   packed  = (int*)(sd + N);
    uint4* hp      = (uint4*)(packed + (size_t)NB * BSTRIDE);

    const int ablocks = (E + CHUNK - 1) / CHUNK;              // 782
    const int lgrid   = ((size_t)N * LPN2 + LBLK - 1) / LBLK; // 3125

    (void)hipMemsetAsync(bcursor, 0, 1024 * sizeof(int), stream);
    partition<<<ablocks, PBLK, 0, stream>>>(x, src, dst, bcursor, packed, xh, E, N, NB);
    sortagg1<<<NB, SBLK, 0, stream>>>(xh, packed, bcursor, Ws1, Wn1, b1, hp, sd, N);
    layer2<<<lgrid, LBLK, 0, stream>>>(hp, packed, sd, Ws2, Wn2, b2, out, N);
}